// Round 5
// baseline (523.969 us; speedup 1.0000x reference)
//
#include <hip/hip_runtime.h>
#include <hip/hip_bf16.h>

// MultiHeadAttentionLayer: B=8, S=1024, D_MODEL=1024, H=16, DK=64. fp32 in/out.
// Round 5: (1) W pre-converted to bf16 -> all GEMM staging via global_load_lds (m97 both
// sides, zero staging VALU) except V-GEMM A-side (fp32 inline cvt, buffer-budget forced);
// (2) V-GEMM epilogue stores V TRANSPOSED [b,h,dv][s] so attention PV B-frags are direct
// contiguous global b128 loads; (3) attention rebuilt on transposed-S: Sᵀ=mfma(K,Q) puts
// a full q-row (16 kv) in-register per lane -> softmax = 15 reg-ops + 2 shfl (was 32 shfl),
// P->A-frag via 2.3KB wave-private LDS strip, ZERO barriers in the S-loop.
// Buffers: ws[0,8)=Wq/Wk/Wv/Wf bf16, ws[8,24)=input conv slot (later ao copy),
// ws[16,32)=vt; d_out[0,16)=qh (attn writes ao in-place), d_out[16,32)=kh.

#define D_MODEL_ 1024
#define NH_ 16
#define DK_ 64
#define B_ 8
#define S_ 1024
#define M_ (B_ * S_)   // 8192 rows

typedef __hip_bfloat16 bf16;
typedef __attribute__((ext_vector_type(8))) short short8;   // 8 bf16 = 4 VGPRs (MFMA A/B frag)
typedef __attribute__((ext_vector_type(4))) short short4_t; // 4 bf16 = 8B
typedef __attribute__((ext_vector_type(4))) float f32x4;    // MFMA C/D frag

typedef const __attribute__((address_space(1))) unsigned int* gas_u32p;
typedef __attribute__((address_space(3))) unsigned int* las_u32p;

__device__ __forceinline__ short f2bs(float x) {
  bf16 h = __float2bfloat16(x);
  return *reinterpret_cast<short*>(&h);
}

// ---------------- fp32 -> bf16 conversion (memory-bound); n = gridDim.x*2048 ----------------
__global__ __launch_bounds__(256)
void conv_f32_bf16(const float* __restrict__ in, bf16* __restrict__ out) {
  size_t i = ((size_t)blockIdx.x * 256 + threadIdx.x) * 8;
  f32x4 a = *(const f32x4*)(in + i);
  f32x4 b = *(const f32x4*)(in + i + 4);
  short8 s;
  s[0] = f2bs(a[0]); s[1] = f2bs(a[1]); s[2] = f2bs(a[2]); s[3] = f2bs(a[3]);
  s[4] = f2bs(b[0]); s[5] = f2bs(b[1]); s[6] = f2bs(b[2]); s[7] = f2bs(b[3]);
  *(short8*)((short*)out + i) = s;
}

// ---------------- MFMA GEMM: C[M,1024] = A[M,1024] @ Wb[1024,1024]^T + bias ----------------
// 128x128 tile, BK=32, 4 waves 2x2. B always bf16 via global_load_lds.
// aF32: 1 = A fp32 (inline cvt staging), 0 = A bf16 (global_load_lds).
// cMode: 0 = bf16 [m][n], 1 = fp32 [m][n], 2 = bf16 transposed vt[(m>>10)*1024+n][m&1023].
__global__ __launch_bounds__(256)
void gemm_mfma(const void* __restrict__ A, const bf16* __restrict__ Wb,
               const float* __restrict__ bias, void* __restrict__ C,
               int aF32, int cMode)
{
  __shared__ short As[128 * 32];
  __shared__ short Bs[128 * 32];
  const int tid = threadIdx.x;
  const int lane = tid & 63;
  const int w = tid >> 6;
  const int l15 = lane & 15, quad = lane >> 4;
  const int wm = (w >> 1) * 64, wn = (w & 1) * 64;
  const int m0 = blockIdx.x * 128, n0 = blockIdx.y * 128;   // m-major dispatch: hot W strip shared

  // staging chunk c = pass*256+tid covers (row=c>>2, kc=(c&3)*8), LDS byte offset c*16
  const int r0 = tid >> 2,          kc0 = (tid & 3) * 8;
  const int r1 = (256 + tid) >> 2,  kc1 = ((256 + tid) & 3) * 8;

  f32x4 acc[4][4];
#pragma unroll
  for (int i = 0; i < 4; ++i)
#pragma unroll
    for (int j = 0; j < 4; ++j)
      acc[i][j] = (f32x4){0.f, 0.f, 0.f, 0.f};

  for (int k0 = 0; k0 < 1024; k0 += 32) {
    __syncthreads();   // protect As/Bs from previous iteration's frag reads
    if (aF32) {
      const float* Af = (const float*)A;
#pragma unroll
      for (int p = 0; p < 2; ++p) {
        int r = p ? r1 : r0, kc = p ? kc1 : kc0;
        const float* g = Af + (size_t)(m0 + r) * 1024 + k0 + kc;
        f32x4 u = *(const f32x4*)g;
        f32x4 v = *(const f32x4*)(g + 4);
        short8 s;
        s[0] = f2bs(u[0]); s[1] = f2bs(u[1]); s[2] = f2bs(u[2]); s[3] = f2bs(u[3]);
        s[4] = f2bs(v[0]); s[5] = f2bs(v[1]); s[6] = f2bs(v[2]); s[7] = f2bs(v[3]);
        *(short8*)&As[r * 32 + kc] = s;
      }
    } else {
      const bf16* Ab = (const bf16*)A;
      __builtin_amdgcn_global_load_lds((gas_u32p)(const void*)(Ab + (size_t)(m0 + r0) * 1024 + k0 + kc0),
          (las_u32p)(void*)((char*)As + w * 1024), 16, 0, 0);
      __builtin_amdgcn_global_load_lds((gas_u32p)(const void*)(Ab + (size_t)(m0 + r1) * 1024 + k0 + kc1),
          (las_u32p)(void*)((char*)As + 4096 + w * 1024), 16, 0, 0);
    }
    // B: bf16 async global->LDS
    __builtin_amdgcn_global_load_lds((gas_u32p)(const void*)(Wb + (size_t)(n0 + r0) * 1024 + k0 + kc0),
        (las_u32p)(void*)((char*)Bs + w * 1024), 16, 0, 0);
    __builtin_amdgcn_global_load_lds((gas_u32p)(const void*)(Wb + (size_t)(n0 + r1) * 1024 + k0 + kc1),
        (las_u32p)(void*)((char*)Bs + 4096 + w * 1024), 16, 0, 0);
    __syncthreads();   // drains vmcnt + lgkm

    short8 af[4], bfv[4];
#pragma unroll
    for (int t = 0; t < 4; ++t) {
      af[t]  = *(short8*)&As[(wm + t * 16 + l15) * 32 + quad * 8];
      bfv[t] = *(short8*)&Bs[(wn + t * 16 + l15) * 32 + quad * 8];
    }
#pragma unroll
    for (int mt = 0; mt < 4; ++mt)
#pragma unroll
      for (int nt = 0; nt < 4; ++nt)
        acc[mt][nt] = __builtin_amdgcn_mfma_f32_16x16x32_bf16(af[mt], bfv[nt], acc[mt][nt], 0, 0, 0);
  }

  // epilogue: C/D layout col=lane&15, row=quad*4+reg
  if (cMode == 2) {
    bf16* vt = (bf16*)C;
    const int bidx = m0 >> 10;          // whole 128-row tile is within one batch
    const int sbase = (m0 & 1023) + wm;
#pragma unroll
    for (int nt = 0; nt < 4; ++nt) {
      int n = n0 + wn + nt * 16 + l15;
      float bv = bias[n];
#pragma unroll
      for (int mt = 0; mt < 4; ++mt) {
        int s = sbase + mt * 16 + quad * 4;
        short4_t pk;
#pragma unroll
        for (int r = 0; r < 4; ++r) pk[r] = f2bs(acc[mt][nt][r] + bv);
        *(short4_t*)((short*)vt + ((size_t)bidx * 1024 + n) * 1024 + s) = pk;
      }
    }
  } else {
#pragma unroll
    for (int nt = 0; nt < 4; ++nt) {
      int col = n0 + wn + nt * 16 + l15;
      float bv = bias[col];
#pragma unroll
      for (int mt = 0; mt < 4; ++mt)
#pragma unroll
        for (int r = 0; r < 4; ++r) {
          int row = m0 + wm + mt * 16 + quad * 4 + r;
          float val = acc[mt][nt][r] + bv;
          if (cMode == 1) ((float*)C)[(size_t)row * 1024 + col] = val;
          else ((bf16*)C)[(size_t)row * 1024 + col] = __float2bfloat16(val);
        }
    }
  }
}

// ---------------- MFMA flash attention, transposed-S, barrier-free ----------------
// Block = (64-q-tile, head, batch); wave w owns q rows q0+w*16..+15 (q_local = lane&15).
// S^T = mfma(K-frag, Q-frag): lane holds 16 kv of q-row l15 -> softmax = reg-reduce + 2 shfl.
// P -> A-frag via wave-private LDS strip. V B-frags direct from global vt[b,h,dv][s].
__global__ __launch_bounds__(256)
void attn_mfma(const bf16* __restrict__ QH, const bf16* __restrict__ KH,
               const bf16* __restrict__ VT, bf16* __restrict__ AO)
{
  __shared__ short Ps[4][16 * 72];   // per-wave strip, 2304 B each
  const int tid = threadIdx.x;
  const int lane = tid & 63;
  const int w = tid >> 6;
  const int l15 = lane & 15, quad = lane >> 4;
  const int q0 = blockIdx.x * 64;
  const int h = blockIdx.y, b = blockIdx.z;
  const size_t base = ((size_t)b * S_) * D_MODEL_ + (size_t)h * DK_;   // QH/KH/AO
  const size_t vtb  = (((size_t)b * NH_ + h) * DK_) * (size_t)S_;      // VT rows (dv)
  const float NEG = -1e30f;
  short* myPs = Ps[w];

  // Q A-frags (once per block; qh region becomes ao later -> must read before any AO store)
  short8 qa[2];
#pragma unroll
  for (int ks = 0; ks < 2; ++ks)
    qa[ks] = *(const short8*)((const short*)QH + base + (size_t)(q0 + w * 16 + l15) * D_MODEL_ + ks * 32 + quad * 8);

  // prefetch tile 0: K frags (A-operand layout) + V^T frags (B-operand layout)
  short8 kb[4][2], vb[4][2];
#pragma unroll
  for (int nt = 0; nt < 4; ++nt)
#pragma unroll
    for (int ks = 0; ks < 2; ++ks) {
      kb[nt][ks] = *(const short8*)((const short*)KH + base + (size_t)(nt * 16 + l15) * D_MODEL_ + ks * 32 + quad * 8);
      vb[nt][ks] = *(const short8*)((const short*)VT + vtb + (size_t)(nt * 16 + l15) * S_ + ks * 32 + quad * 8);
    }

  float mi = NEG, li = 0.f;
  f32x4 oacc[4];
#pragma unroll
  for (int nt = 0; nt < 4; ++nt) oacc[nt] = (f32x4){0.f, 0.f, 0.f, 0.f};

  for (int j0 = 0; j0 < S_; j0 += 64) {
    // S^T tiles: A=K (m=kv), B=Q (n=q) -> lane: col q=l15, rows kv=nt*16+quad*4+r
    f32x4 sacc[4];
#pragma unroll
    for (int nt = 0; nt < 4; ++nt) sacc[nt] = (f32x4){0.f, 0.f, 0.f, 0.f};
#pragma unroll
    for (int nt = 0; nt < 4; ++nt)
#pragma unroll
      for (int ks = 0; ks < 2; ++ks)
        sacc[nt] = __builtin_amdgcn_mfma_f32_16x16x32_bf16(kb[nt][ks], qa[ks], sacc[nt], 0, 0, 0);

    const int jn = j0 + 64;
    if (jn < S_) {   // prefetch next K frags (overlaps softmax+PV)
#pragma unroll
      for (int nt = 0; nt < 4; ++nt)
#pragma unroll
        for (int ks = 0; ks < 2; ++ks)
          kb[nt][ks] = *(const short8*)((const short*)KH + base + (size_t)(jn + nt * 16 + l15) * D_MODEL_ + ks * 32 + quad * 8);
    }

    // softmax over the 16 in-register kv values of q-row l15 (+ cross-quad shfl)
    float p[4][4], rm = NEG;
#pragma unroll
    for (int nt = 0; nt < 4; ++nt)
#pragma unroll
      for (int r = 0; r < 4; ++r) {
        float x = sacc[nt][r] * 0.125f;          // / sqrt(dk)
        if (x == 0.0f) x = NEG;                  // faithful scalar-equality mask
        p[nt][r] = x;
        rm = fmaxf(rm, x);
      }
    rm = fmaxf(rm, __shfl_xor(rm, 16, 64));
    rm = fmaxf(rm, __shfl_xor(rm, 32, 64));
    float nm = fmaxf(mi, rm);
    float alpha = __expf(mi - nm);
    float ps = 0.f;
#pragma unroll
    for (int nt = 0; nt < 4; ++nt)
#pragma unroll
      for (int r = 0; r < 4; ++r) {
        float e = __expf(p[nt][r] - nm);
        p[nt][r] = e;
        ps += e;
      }
    ps += __shfl_xor(ps, 16, 64);
    ps += __shfl_xor(ps, 32, 64);
    li = li * alpha + ps;
    mi = nm;

    // P -> wave-private LDS strip [q=l15][kv], kv chunk nt*16+quad*4 (b64 writes)
#pragma unroll
    for (int nt = 0; nt < 4; ++nt) {
      short4_t pk;
#pragma unroll
      for (int r = 0; r < 4; ++r) pk[r] = f2bs(p[nt][r]);
      *(short4_t*)&myPs[l15 * 72 + nt * 16 + quad * 4] = pk;
    }

    // rescale O: O rows are q_local=quad*4+r -> fetch alpha from lane l15'=quad*4+r
    float ar[4];
#pragma unroll
    for (int r = 0; r < 4; ++r) ar[r] = __shfl(alpha, quad * 4 + r, 64);
#pragma unroll
    for (int nt = 0; nt < 4; ++nt)
#pragma unroll
      for (int r = 0; r < 4; ++r) oacc[nt][r] *= ar[r];

    __threadfence_block();   // order Ps writes before same-wave b128 reads

    short8 pa[2];
#pragma unroll
    for (int ks = 0; ks < 2; ++ks)
      pa[ks] = *(short8*)&myPs[l15 * 72 + ks * 32 + quad * 8];
#pragma unroll
    for (int nt = 0; nt < 4; ++nt)
#pragma unroll
      for (int ks = 0; ks < 2; ++ks)
        oacc[nt] = __builtin_amdgcn_mfma_f32_16x16x32_bf16(pa[ks], vb[nt][ks], oacc[nt], 0, 0, 0);

    if (jn < S_) {   // prefetch next V^T frags
#pragma unroll
      for (int nt = 0; nt < 4; ++nt)
#pragma unroll
        for (int ks = 0; ks < 2; ++ks)
          vb[nt][ks] = *(const short8*)((const short*)VT + vtb + (size_t)(nt * 16 + l15) * S_ + jn + ks * 32 + quad * 8);
    }
  }

  // epilogue: O rows q_local=quad*4+r, cols dv=nt*16+l15; li lives at lane l15'=q_local
  float lr[4];
#pragma unroll
  for (int r = 0; r < 4; ++r) lr[r] = __shfl(li, quad * 4 + r, 64);
#pragma unroll
  for (int r = 0; r < 4; ++r) {
    float inv = (lr[r] > 0.f) ? 1.0f / lr[r] : 0.f;
    int q = q0 + w * 16 + quad * 4 + r;
#pragma unroll
    for (int nt = 0; nt < 4; ++nt)
      AO[base + (size_t)q * D_MODEL_ + nt * 16 + l15] = __float2bfloat16(oacc[nt][r] * inv);
  }
}

extern "C" void kernel_launch(void* const* d_in, const int* in_sizes, int n_in,
                              void* d_out, int out_size, void* d_ws, size_t ws_size,
                              hipStream_t stream) {
  (void)in_sizes; (void)n_in; (void)out_size; (void)ws_size;
  const float* q  = (const float*)d_in[0];
  const float* k  = (const float*)d_in[1];
  const float* v  = (const float*)d_in[2];
  const float* Wq = (const float*)d_in[3];
  const float* bq = (const float*)d_in[4];
  const float* Wk = (const float*)d_in[5];
  const float* bk = (const float*)d_in[6];
  const float* Wv = (const float*)d_in[7];
  const float* bv = (const float*)d_in[8];
  const float* Wf = (const float*)d_in[9];
  const float* bF = (const float*)d_in[10];

  const size_t MB = (size_t)1024 * 1024;
  char* ws = (char*)d_ws;
  bf16* wqb = (bf16*)(ws);                 // [0,2) MiB
  bf16* wkb = (bf16*)(ws + 2 * MB);        // [2,4)
  bf16* wvb = (bf16*)(ws + 4 * MB);        // [4,6)
  bf16* wfb = (bf16*)(ws + 6 * MB);        // [6,8)
  bf16* inb = (bf16*)(ws + 8 * MB);        // [8,24) input conv slot / ao copy
  bf16* vt  = (bf16*)(ws + 16 * MB);       // [16,32) transposed V (alive after k-GEMM)
  bf16* qh  = (bf16*)d_out;                // d_out [0,16): qh -> ao in-place
  bf16* kh  = (bf16*)((char*)d_out + 16 * MB);

  dim3 blk(256);
  dim3 wgrid(512);                          // 1M elems
  dim3 igrid(4096);                         // 8M elems
  dim3 ggrid(M_ / 128, D_MODEL_ / 128);     // (64, 8) m-major

  conv_f32_bf16<<<wgrid, blk, 0, stream>>>(Wq, wqb);
  conv_f32_bf16<<<wgrid, blk, 0, stream>>>(Wk, wkb);
  conv_f32_bf16<<<wgrid, blk, 0, stream>>>(Wv, wvb);
  conv_f32_bf16<<<wgrid, blk, 0, stream>>>(Wf, wfb);

  conv_f32_bf16<<<igrid, blk, 0, stream>>>(q, inb);
  gemm_mfma<<<ggrid, blk, 0, stream>>>(inb, wqb, bq, qh, 0, 0);
  conv_f32_bf16<<<igrid, blk, 0, stream>>>(k, inb);
  gemm_mfma<<<ggrid, blk, 0, stream>>>(inb, wkb, bk, kh, 0, 0);
  gemm_mfma<<<ggrid, blk, 0, stream>>>(v, wvb, bv, vt, 1, 2);   // fp32 A inline, vt store

  attn_mfma<<<dim3(S_ / 64, NH_, B_), blk, 0, stream>>>(qh, kh, vt, qh);  // ao over qh

  hipMemcpyAsync(inb, d_out, 16 * MB, hipMemcpyDeviceToDevice, stream);   // park ao
  gemm_mfma<<<ggrid, blk, 0, stream>>>(inb, wfb, bF, d_out, 0, 1);
}

// Round 6
// 357.935 us; speedup vs baseline: 1.4639x; 1.4639x over previous
//
#include <hip/hip_runtime.h>
#include <hip/hip_bf16.h>

// MultiHeadAttentionLayer: B=8, S=1024, D_MODEL=1024, H=16, DK=64. fp32 in/out.
// Round 6: (1) attn K/V staged ONCE per block into LDS via global_load_lds (R5 had each
// wave privately re-loading identical frags from global -> 4x redundant VMEM, latency-bound
// at 23% VALU / 5.7% MFMA); keeps R5's transposed-S softmax (2 shfl) + wave-private Ps.
// (2) GEMM BK 32->64: halves barrier-drain count (the dominant GEMM cost at 2 blocks/CU).
// (3) 4 W-convs fused into one launch.
// Buffers: ws[0,8)=W bf16 x4, ws[8,24)=input conv slot (later ao copy), ws[16,32)=vt;
// d_out[0,16)=qh->ao in-place, d_out[16,32)=kh.

#define D_MODEL_ 1024
#define NH_ 16
#define DK_ 64
#define B_ 8
#define S_ 1024
#define M_ (B_ * S_)   // 8192 rows

typedef __hip_bfloat16 bf16;
typedef __attribute__((ext_vector_type(8))) short short8;   // 8 bf16 = 4 VGPRs (MFMA A/B frag)
typedef __attribute__((ext_vector_type(4))) short short4_t; // 4 bf16 = 8B
typedef __attribute__((ext_vector_type(4))) float f32x4;    // MFMA C/D frag

typedef const __attribute__((address_space(1))) unsigned int* gas_u32p;
typedef __attribute__((address_space(3))) unsigned int* las_u32p;

__device__ __forceinline__ short f2bs(float x) {
  bf16 h = __float2bfloat16(x);
  return *reinterpret_cast<short*>(&h);
}

// ---------------- fp32 -> bf16 conversion (memory-bound) ----------------
__global__ __launch_bounds__(256)
void conv_f32_bf16(const float* __restrict__ in, bf16* __restrict__ out) {
  size_t i = ((size_t)blockIdx.x * 256 + threadIdx.x) * 8;
  f32x4 a = *(const f32x4*)(in + i);
  f32x4 b = *(const f32x4*)(in + i + 4);
  short8 s;
  s[0] = f2bs(a[0]); s[1] = f2bs(a[1]); s[2] = f2bs(a[2]); s[3] = f2bs(a[3]);
  s[4] = f2bs(b[0]); s[5] = f2bs(b[1]); s[6] = f2bs(b[2]); s[7] = f2bs(b[3]);
  *(short8*)((short*)out + i) = s;
}

// fused 4-weight conversion: z selects source; dst = base + z*1M elems
__global__ __launch_bounds__(256)
void conv_w4(const float* __restrict__ w0, const float* __restrict__ w1,
             const float* __restrict__ w2, const float* __restrict__ w3,
             bf16* __restrict__ out) {
  const float* src = (blockIdx.z == 0) ? w0 : (blockIdx.z == 1) ? w1
                   : (blockIdx.z == 2) ? w2 : w3;
  size_t i = ((size_t)blockIdx.x * 256 + threadIdx.x) * 8;
  f32x4 a = *(const f32x4*)(src + i);
  f32x4 b = *(const f32x4*)(src + i + 4);
  short8 s;
  s[0] = f2bs(a[0]); s[1] = f2bs(a[1]); s[2] = f2bs(a[2]); s[3] = f2bs(a[3]);
  s[4] = f2bs(b[0]); s[5] = f2bs(b[1]); s[6] = f2bs(b[2]); s[7] = f2bs(b[3]);
  *(short8*)((short*)out + (size_t)blockIdx.z * 1024 * 1024 + i) = s;
}

// ---------------- MFMA GEMM: C[M,1024] = A[M,1024] @ Wb[1024,1024]^T + bias -------------
// 128x128 tile, BK=64 (16 iters), 4 waves 2x2. Sub-tiles As[kk]/Bs[kk]: k in [32kk,32kk+32).
// aF32: 1 = A fp32 (inline cvt staging), 0 = A bf16 (global_load_lds).
// cMode: 0 = bf16 [m][n], 1 = fp32 [m][n], 2 = bf16 transposed vt[(m>>10)*1024+n][m&1023].
__global__ __launch_bounds__(256)
void gemm_mfma(const void* __restrict__ A, const bf16* __restrict__ Wb,
               const float* __restrict__ bias, void* __restrict__ C,
               int aF32, int cMode)
{
  __shared__ short As[2][128 * 32];
  __shared__ short Bs[2][128 * 32];
  const int tid = threadIdx.x;
  const int lane = tid & 63;
  const int w = tid >> 6;
  const int l15 = lane & 15, quad = lane >> 4;
  const int wm = (w >> 1) * 64, wn = (w & 1) * 64;
  const int m0 = blockIdx.x * 128, n0 = blockIdx.y * 128;   // m-major dispatch

  // global_load_lds lane map: instr (sub,p) covers rows 32w+16p+(lane>>2), k-chunk
  // sub*32+(lane&3)*8; LDS offset = sub-base + w*2048 + p*1024 + lane*16  (derived exact)
  const int srow = (lane >> 2);
  const int skc  = (lane & 3) * 8;

  f32x4 acc[4][4];
#pragma unroll
  for (int i = 0; i < 4; ++i)
#pragma unroll
    for (int j = 0; j < 4; ++j)
      acc[i][j] = (f32x4){0.f, 0.f, 0.f, 0.f};

  for (int k0 = 0; k0 < 1024; k0 += 64) {
    __syncthreads();   // protect As/Bs from previous iteration's frag reads
    if (aF32) {
      const float* Af = (const float*)A;
#pragma unroll
      for (int p = 0; p < 4; ++p) {
        int c = p * 256 + tid;              // 0..1023 = 128 rows x 8 chunks
        int r = c >> 3, kc = (c & 7) * 8;
        const float* g = Af + (size_t)(m0 + r) * 1024 + k0 + kc;
        f32x4 u = *(const f32x4*)g;
        f32x4 v = *(const f32x4*)(g + 4);
        short8 s;
        s[0] = f2bs(u[0]); s[1] = f2bs(u[1]); s[2] = f2bs(u[2]); s[3] = f2bs(u[3]);
        s[4] = f2bs(v[0]); s[5] = f2bs(v[1]); s[6] = f2bs(v[2]); s[7] = f2bs(v[3]);
        *(short8*)&As[kc >> 5][r * 32 + (kc & 31)] = s;
      }
    } else {
      const bf16* Ab = (const bf16*)A;
#pragma unroll
      for (int sub = 0; sub < 2; ++sub)
#pragma unroll
        for (int p = 0; p < 2; ++p) {
          int r = 32 * w + 16 * p + srow;
          __builtin_amdgcn_global_load_lds(
              (gas_u32p)(const void*)(Ab + (size_t)(m0 + r) * 1024 + k0 + sub * 32 + skc),
              (las_u32p)(void*)((char*)&As[sub][0] + w * 2048 + p * 1024), 16, 0, 0);
        }
    }
#pragma unroll
    for (int sub = 0; sub < 2; ++sub)
#pragma unroll
      for (int p = 0; p < 2; ++p) {
        int r = 32 * w + 16 * p + srow;
        __builtin_amdgcn_global_load_lds(
            (gas_u32p)(const void*)(Wb + (size_t)(n0 + r) * 1024 + k0 + sub * 32 + skc),
            (las_u32p)(void*)((char*)&Bs[sub][0] + w * 2048 + p * 1024), 16, 0, 0);
      }
    __syncthreads();   // drains vmcnt + lgkm

#pragma unroll
    for (int kk = 0; kk < 2; ++kk) {
      short8 af[4], bfv[4];
#pragma unroll
      for (int t = 0; t < 4; ++t) {
        af[t]  = *(short8*)&As[kk][(wm + t * 16 + l15) * 32 + quad * 8];
        bfv[t] = *(short8*)&Bs[kk][(wn + t * 16 + l15) * 32 + quad * 8];
      }
#pragma unroll
      for (int mt = 0; mt < 4; ++mt)
#pragma unroll
        for (int nt = 0; nt < 4; ++nt)
          acc[mt][nt] = __builtin_amdgcn_mfma_f32_16x16x32_bf16(af[mt], bfv[nt], acc[mt][nt], 0, 0, 0);
    }
  }

  // epilogue: C/D layout col=lane&15, row=quad*4+reg
  if (cMode == 2) {
    bf16* vt = (bf16*)C;
    const int bidx = m0 >> 10;
    const int sbase = (m0 & 1023) + wm;
#pragma unroll
    for (int nt = 0; nt < 4; ++nt) {
      int n = n0 + wn + nt * 16 + l15;
      float bv = bias[n];
#pragma unroll
      for (int mt = 0; mt < 4; ++mt) {
        int s = sbase + mt * 16 + quad * 4;
        short4_t pk;
#pragma unroll
        for (int r = 0; r < 4; ++r) pk[r] = f2bs(acc[mt][nt][r] + bv);
        *(short4_t*)((short*)vt + ((size_t)bidx * 1024 + n) * 1024 + s) = pk;
      }
    }
  } else {
#pragma unroll
    for (int nt = 0; nt < 4; ++nt) {
      int col = n0 + wn + nt * 16 + l15;
      float bv = bias[col];
#pragma unroll
      for (int mt = 0; mt < 4; ++mt)
#pragma unroll
        for (int r = 0; r < 4; ++r) {
          int row = m0 + wm + mt * 16 + quad * 4 + r;
          float val = acc[mt][nt][r] + bv;
          if (cMode == 1) ((float*)C)[(size_t)row * 1024 + col] = val;
          else ((bf16*)C)[(size_t)row * 1024 + col] = __float2bfloat16(val);
        }
    }
  }
}

// ---------------- MFMA flash attention: shared-LDS K/V, transposed-S ----------------
// Block = (64-q-tile, head, batch); wave w owns q rows q0+w*16..+15.
// K tile and V^T tile staged once per block via global_load_lds (coalesced, zero VALU);
// frags via ds_read_b128. S^T = mfma(K,Q) -> lane holds 16 kv of q-row l15; softmax =
// reg-reduce + 2 shfl; P -> A-frag via wave-private LDS strip; PV B-frags from Vs.
__global__ __launch_bounds__(256)
void attn_mfma(const bf16* __restrict__ QH, const bf16* __restrict__ KH,
               const bf16* __restrict__ VT, bf16* __restrict__ AO)
{
  __shared__ short Ks[2][64 * 32];   // sub ks: dk in [32ks,32ks+32)
  __shared__ short Vs[2][64 * 32];   // sub ks: s_local in [32ks,32ks+32), rows dv
  __shared__ short Ps[4][16 * 72];   // per-wave strip
  const int tid = threadIdx.x;
  const int lane = tid & 63;
  const int w = tid >> 6;
  const int l15 = lane & 15, quad = lane >> 4;
  const int q0 = blockIdx.x * 64;
  const int h = blockIdx.y, b = blockIdx.z;
  const size_t base = ((size_t)b * S_) * D_MODEL_ + (size_t)h * DK_;   // QH/KH/AO
  const size_t vtb  = (((size_t)b * NH_ + h) * DK_) * (size_t)S_;      // VT rows (dv)
  const float NEG = -1e30f;
  short* myPs = Ps[w];

  // staging lane map: rows 16w+(lane>>2), chunk (lane&3)*8; LDS = sub-base + w*1024 + lane*16
  const int srow = 16 * w + (lane >> 2);
  const int skc  = (lane & 3) * 8;

  // Q A-frags (once per block; read before any AO store - ao aliases qh)
  short8 qa[2];
#pragma unroll
  for (int ks = 0; ks < 2; ++ks)
    qa[ks] = *(const short8*)((const short*)QH + base + (size_t)(q0 + w * 16 + l15) * D_MODEL_ + ks * 32 + quad * 8);

  float mi = NEG, li = 0.f;
  f32x4 oacc[4];
#pragma unroll
  for (int nt = 0; nt < 4; ++nt) oacc[nt] = (f32x4){0.f, 0.f, 0.f, 0.f};

  for (int j0 = 0; j0 < S_; j0 += 64) {
    __syncthreads();   // protect Ks/Vs from previous iteration's readers
#pragma unroll
    for (int sub = 0; sub < 2; ++sub) {
      __builtin_amdgcn_global_load_lds(
          (gas_u32p)(const void*)((const short*)KH + base + (size_t)(j0 + srow) * D_MODEL_ + sub * 32 + skc),
          (las_u32p)(void*)((char*)&Ks[sub][0] + w * 1024), 16, 0, 0);
      __builtin_amdgcn_global_load_lds(
          (gas_u32p)(const void*)((const short*)VT + vtb + (size_t)srow * S_ + j0 + sub * 32 + skc),
          (las_u32p)(void*)((char*)&Vs[sub][0] + w * 1024), 16, 0, 0);
    }
    __syncthreads();   // drains vmcnt

    // frag reads (b128 from LDS, shared across waves)
    short8 kb[4][2], vb[4][2];
#pragma unroll
    for (int nt = 0; nt < 4; ++nt)
#pragma unroll
      for (int ks = 0; ks < 2; ++ks) {
        kb[nt][ks] = *(short8*)&Ks[ks][(nt * 16 + l15) * 32 + quad * 8];
        vb[nt][ks] = *(short8*)&Vs[ks][(nt * 16 + l15) * 32 + quad * 8];
      }

    // S^T: A=K (m=kv), B=Q (n=q) -> lane: q=l15, kv rows nt*16+quad*4+r
    f32x4 sacc[4];
#pragma unroll
    for (int nt = 0; nt < 4; ++nt) sacc[nt] = (f32x4){0.f, 0.f, 0.f, 0.f};
#pragma unroll
    for (int nt = 0; nt < 4; ++nt)
#pragma unroll
      for (int ks = 0; ks < 2; ++ks)
        sacc[nt] = __builtin_amdgcn_mfma_f32_16x16x32_bf16(kb[nt][ks], qa[ks], sacc[nt], 0, 0, 0);

    // softmax over 16 in-register kv values of q-row l15 (+2 shfl across quads)
    float p[4][4], rm = NEG;
#pragma unroll
    for (int nt = 0; nt < 4; ++nt)
#pragma unroll
      for (int r = 0; r < 4; ++r) {
        float x = sacc[nt][r] * 0.125f;          // / sqrt(dk)
        if (x == 0.0f) x = NEG;                  // faithful scalar-equality mask
        p[nt][r] = x;
        rm = fmaxf(rm, x);
      }
    rm = fmaxf(rm, __shfl_xor(rm, 16, 64));
    rm = fmaxf(rm, __shfl_xor(rm, 32, 64));
    float nm = fmaxf(mi, rm);
    float alpha = __expf(mi - nm);
    float ps = 0.f;
#pragma unroll
    for (int nt = 0; nt < 4; ++nt)
#pragma unroll
      for (int r = 0; r < 4; ++r) {
        float e = __expf(p[nt][r] - nm);
        p[nt][r] = e;
        ps += e;
      }
    ps += __shfl_xor(ps, 16, 64);
    ps += __shfl_xor(ps, 32, 64);
    li = li * alpha + ps;
    mi = nm;

    // P -> wave-private LDS strip [q=l15][kv]
#pragma unroll
    for (int nt = 0; nt < 4; ++nt) {
      short4_t pk;
#pragma unroll
      for (int r = 0; r < 4; ++r) pk[r] = f2bs(p[nt][r]);
      *(short4_t*)&myPs[l15 * 72 + nt * 16 + quad * 4] = pk;
    }

    // rescale O: O rows q_local=quad*4+r; alpha lives at lane l15'=q_local
    float ar[4];
#pragma unroll
    for (int r = 0; r < 4; ++r) ar[r] = __shfl(alpha, quad * 4 + r, 64);
#pragma unroll
    for (int nt = 0; nt < 4; ++nt)
#pragma unroll
      for (int r = 0; r < 4; ++r) oacc[nt][r] *= ar[r];

    __threadfence_block();   // order Ps writes before same-wave b128 reads

    short8 pa[2];
#pragma unroll
    for (int ks = 0; ks < 2; ++ks)
      pa[ks] = *(short8*)&myPs[l15 * 72 + ks * 32 + quad * 8];
#pragma unroll
    for (int nt = 0; nt < 4; ++nt)
#pragma unroll
      for (int ks = 0; ks < 2; ++ks)
        oacc[nt] = __builtin_amdgcn_mfma_f32_16x16x32_bf16(pa[ks], vb[nt][ks], oacc[nt], 0, 0, 0);
  }

  // epilogue: O rows q_local=quad*4+r, cols dv=nt*16+l15; li at lane l15'=q_local
  float lr[4];
#pragma unroll
  for (int r = 0; r < 4; ++r) lr[r] = __shfl(li, quad * 4 + r, 64);
#pragma unroll
  for (int r = 0; r < 4; ++r) {
    float inv = (lr[r] > 0.f) ? 1.0f / lr[r] : 0.f;
    int q = q0 + w * 16 + quad * 4 + r;
#pragma unroll
    for (int nt = 0; nt < 4; ++nt)
      AO[base + (size_t)q * D_MODEL_ + nt * 16 + l15] = __float2bfloat16(oacc[nt][r] * inv);
  }
}

extern "C" void kernel_launch(void* const* d_in, const int* in_sizes, int n_in,
                              void* d_out, int out_size, void* d_ws, size_t ws_size,
                              hipStream_t stream) {
  (void)in_sizes; (void)n_in; (void)out_size; (void)ws_size;
  const float* q  = (const float*)d_in[0];
  const float* k  = (const float*)d_in[1];
  const float* v  = (const float*)d_in[2];
  const float* Wq = (const float*)d_in[3];
  const float* bq = (const float*)d_in[4];
  const float* Wk = (const float*)d_in[5];
  const float* bk = (const float*)d_in[6];
  const float* Wv = (const float*)d_in[7];
  const float* bv = (const float*)d_in[8];
  const float* Wf = (const float*)d_in[9];
  const float* bF = (const float*)d_in[10];

  const size_t MB = (size_t)1024 * 1024;
  char* ws = (char*)d_ws;
  bf16* wb4 = (bf16*)(ws);                 // [0,8): Wq|Wk|Wv|Wf bf16
  bf16* wqb = wb4;
  bf16* wkb = (bf16*)(ws + 2 * MB);
  bf16* wvb = (bf16*)(ws + 4 * MB);
  bf16* wfb = (bf16*)(ws + 6 * MB);
  bf16* inb = (bf16*)(ws + 8 * MB);        // [8,24) input conv slot / ao copy
  bf16* vt  = (bf16*)(ws + 16 * MB);       // [16,32) transposed V
  bf16* qh  = (bf16*)d_out;                // d_out [0,16): qh -> ao in-place
  bf16* kh  = (bf16*)((char*)d_out + 16 * MB);

  dim3 blk(256);
  dim3 igrid(4096);                         // 8M elems
  dim3 ggrid(M_ / 128, D_MODEL_ / 128);     // (64, 8) m-major

  conv_w4<<<dim3(512, 1, 4), blk, 0, stream>>>(Wq, Wk, Wv, Wf, wb4);

  conv_f32_bf16<<<igrid, blk, 0, stream>>>(q, inb);
  gemm_mfma<<<ggrid, blk, 0, stream>>>(inb, wqb, bq, qh, 0, 0);
  conv_f32_bf16<<<igrid, blk, 0, stream>>>(k, inb);
  gemm_mfma<<<ggrid, blk, 0, stream>>>(inb, wkb, bk, kh, 0, 0);
  gemm_mfma<<<ggrid, blk, 0, stream>>>(v, wvb, bv, vt, 1, 2);   // fp32 A inline, vt store

  attn_mfma<<<dim3(S_ / 64, NH_, B_), blk, 0, stream>>>(qh, kh, vt, qh);  // ao over qh

  hipMemcpyAsync(inb, d_out, 16 * MB, hipMemcpyDeviceToDevice, stream);   // park ao
  gemm_mfma<<<ggrid, blk, 0, stream>>>(inb, wfb, bF, d_out, 0, 1);
}